// Round 1
// 334.544 us; speedup vs baseline: 1.0070x; 1.0070x over previous
//
#include <hip/hip_runtime.h>
#include <hip/hip_fp16.h>

#define NBSHIFT 8
#define BSZ     256     // nodes per bucket
#define CAP     5120    // fixed bucket capacity (mean 4092, sigma 64 -> +16 sigma)

typedef _Float16 f16x8 __attribute__((ext_vector_type(8)));
typedef float    f32x4 __attribute__((ext_vector_type(4)));

// ---------------- self-contained MFMA GEMM body ----------------
// Per block: (a) vd = W_d @ att_d into LDS (128 threads, L1-resident row dots);
// (b) W_s transposed+cvt to fp16 LDS sWh[n][k] (coalesced loads, 8B LDS stores);
// then Y(fp16)=X@W via mfma_f32_16x16x32_f16, wave owns 16 rows.
// A-frag from X (f32 input for layer 1, fp16 input for layer 2).
// C/D: col=lane&15, row=quad*4+reg.

#define GEMM_LDS_BYTES (128 * 136 * 2 + 512)

template <bool XHALF>
__device__ __forceinline__ void gemm_body(
        const void* __restrict__ Xv, const float* __restrict__ Ws,
        const float* __restrict__ Wd, const float* __restrict__ attd,
        const float* __restrict__ att,
        __half* __restrict__ Y, float* __restrict__ a_s, float* __restrict__ a_d,
        int N, int blk, char* smem) {
    _Float16 (*sWh)[136] = (_Float16(*)[136])smem;
    float* svd = (float*)(smem + 128 * 136 * 2);
    int t = threadIdx.x;

    // vd[k] = dot(Wd row k, attd)   (t < 128; rows L1-cached across the 32 iters)
    if (t < 128) {
        const float4* wr = (const float4*)&Wd[t * 128];
        const float4* ar = (const float4*)attd;
        float s = 0.f;
#pragma unroll 8
        for (int j = 0; j < 32; j++) {
            float4 w = wr[j], a = ar[j];
            s += w.x * a.x + w.y * a.y + w.z * a.z + w.w * a.w;
        }
        svd[t] = s;
    }
    // sWh[n][k] = (fp16) Ws[k*128+n]; per-j loads coalesced (lanes span n)
#pragma unroll
    for (int i = 0; i < 16; i++) {
        int gid = t + i * 256;       // 0..4095
        int n = gid & 127, kq = gid >> 7;
        _Float16 p[4];
        p[0] = (_Float16)Ws[(kq * 4 + 0) * 128 + n];
        p[1] = (_Float16)Ws[(kq * 4 + 1) * 128 + n];
        p[2] = (_Float16)Ws[(kq * 4 + 2) * 128 + n];
        p[3] = (_Float16)Ws[(kq * 4 + 3) * 128 + n];
        *(uint2*)&sWh[n][kq * 4] = *(uint2*)p;
    }
    __syncthreads();

    int l = t & 63, wv = t >> 6;
    int quad = l >> 4, lm = l & 15;
    int rbase = blk * 64 + wv * 16;
    int arow = rbase + lm;
    bool rok = arow < N;

    f32x4 acc[8];
#pragma unroll
    for (int c = 0; c < 8; c++) acc[c] = (f32x4){0.f, 0.f, 0.f, 0.f};
    float adp = 0.f;

#pragma unroll
    for (int kc = 0; kc < 4; kc++) {
        int k0 = kc * 32 + quad * 8;
        float xf[8];
        f16x8 af;
        if constexpr (XHALF) {
            const __half* xrow = (const __half*)Xv + (size_t)arow * 128;
            if (rok) {
                af = *(const f16x8*)&xrow[k0];
            } else {
#pragma unroll
                for (int j = 0; j < 8; j++) af[j] = (_Float16)0.f;
            }
#pragma unroll
            for (int j = 0; j < 8; j++) xf[j] = (float)af[j];
        } else {
            const float* xrow = (const float*)Xv + (size_t)arow * 128;
            if (rok) {
                *(float4*)&xf[0] = *(const float4*)&xrow[k0];
                *(float4*)&xf[4] = *(const float4*)&xrow[k0 + 4];
            } else {
#pragma unroll
                for (int j = 0; j < 8; j++) xf[j] = 0.f;
            }
#pragma unroll
            for (int j = 0; j < 8; j++) af[j] = (_Float16)xf[j];
        }
        float4 v0 = *(const float4*)&svd[k0];       // broadcast within quad
        float4 v1 = *(const float4*)&svd[k0 + 4];
        adp += xf[0] * v0.x + xf[1] * v0.y + xf[2] * v0.z + xf[3] * v0.w
             + xf[4] * v1.x + xf[5] * v1.y + xf[6] * v1.z + xf[7] * v1.w;
#pragma unroll
        for (int c = 0; c < 8; c++) {
            f16x8 bf = *(const f16x8*)&sWh[c * 16 + lm][k0];   // col n = c*16+lm
            acc[c] = __builtin_amdgcn_mfma_f32_16x16x32_f16(af, bf, acc[c], 0, 0, 0);
        }
    }

    adp += __shfl_xor(adp, 16);
    adp += __shfl_xor(adp, 32);
    if (quad == 0 && rok) a_d[arow] = adp;

    float attc[8];
#pragma unroll
    for (int c = 0; c < 8; c++) attc[c] = att[c * 16 + lm];
#pragma unroll
    for (int r = 0; r < 4; r++) {
        int grow = rbase + quad * 4 + r;
        bool gok = grow < N;
        float p = 0.f;
#pragma unroll
        for (int c = 0; c < 8; c++) {
            if (gok) Y[(size_t)grow * 128 + c * 16 + lm] = __float2half(acc[c][r]);
            p += acc[c][r] * attc[c];
        }
        p += __shfl_xor(p, 1); p += __shfl_xor(p, 2); p += __shfl_xor(p, 4); p += __shfl_xor(p, 8);
        if (lm == 0 && gok) a_s[grow] = p;
    }
}

// ---------------- FUSED: layer-1 GEMM (blocks < gb) + kA3 pair placement ----------------
__global__ __launch_bounds__(256, 4) void k_fuse1(
        const float* __restrict__ X, const float* __restrict__ W1s,
        const float* __restrict__ W1d, const float* __restrict__ a1d,
        const float* __restrict__ a1s,
        __half* __restrict__ Y, float* __restrict__ a_s, float* __restrict__ a_d, int N, int gb,
        const int* __restrict__ src, const int* __restrict__ dst, int E,
        int* __restrict__ cursor, unsigned* __restrict__ pairs) {
    __shared__ __align__(16) char smem[GEMM_LDS_BYTES];
    int t = threadIdx.x;

    if ((int)blockIdx.x >= gb) {
        // ---- kA3: bucket pair placement (LDS-aggregated claims) ----
        int* hist  = (int*)smem;          // 512 ints
        int* start = hist + 512;          // 512 ints
        hist[t] = 0; hist[t + 256] = 0;
        __syncthreads();
        int e0 = (blockIdx.x - gb) * 1024 + t * 4;
        int d[4], s[4];
        bool full = (e0 + 3 < E);
        if (full) {
            int4 dv = *(const int4*)&dst[e0];
            int4 sv = *(const int4*)&src[e0];
            d[0] = dv.x; d[1] = dv.y; d[2] = dv.z; d[3] = dv.w;
            s[0] = sv.x; s[1] = sv.y; s[2] = sv.z; s[3] = sv.w;
#pragma unroll
            for (int i = 0; i < 4; i++) atomicAdd(&hist[d[i] >> NBSHIFT], 1);
        } else {
#pragma unroll
            for (int i = 0; i < 4; i++) {
                if (e0 + i < E) { d[i] = dst[e0 + i]; s[i] = src[e0 + i]; atomicAdd(&hist[d[i] >> NBSHIFT], 1); }
                else d[i] = -1;
            }
        }
        __syncthreads();
        if (hist[t] > 0)       start[t]       = atomicAdd(&cursor[t],       hist[t]);
        if (hist[t + 256] > 0) start[t + 256] = atomicAdd(&cursor[t + 256], hist[t + 256]);
        __syncthreads();
        hist[t] = 0; hist[t + 256] = 0;   // reuse as rank counters
        __syncthreads();
#pragma unroll
        for (int i = 0; i < 4; i++) {
            if (full || (e0 + i < E)) {
                int b = d[i] >> NBSHIFT;
                int r = atomicAdd(&hist[b], 1);
                pairs[b * CAP + start[b] + r] = ((unsigned)(d[i] & (BSZ - 1)) << 17) | (unsigned)s[i];
            }
        }
        return;
    }

    gemm_body<false>(X, W1s, W1d, a1d, a1s, Y, a_s, a_d, N, blockIdx.x, smem);
}

// ---------------- standalone layer-2 GEMM (fp16 input h) ----------------
__global__ __launch_bounds__(256, 4) void k_gemm2(
        const __half* __restrict__ X, const float* __restrict__ W2s,
        const float* __restrict__ W2d, const float* __restrict__ a2d,
        const float* __restrict__ a2s,
        __half* __restrict__ Y, float* __restrict__ a_s, float* __restrict__ a_d, int N) {
    __shared__ __align__(16) char smem[GEMM_LDS_BYTES];
    gemm_body<true>(X, W2s, W2d, a2d, a2s, Y, a_s, a_d, N, blockIdx.x, smem);
}

// ---------------- kB: per-bucket CSR finalize (counts/scan/place in LDS) ----------------
__global__ __launch_bounds__(256) void kB_csr(const unsigned* __restrict__ pairs,
                                              const int* __restrict__ cursor,
                                              int* __restrict__ row_start, int* __restrict__ row_end,
                                              int* __restrict__ csr_src, int N) {
    __shared__ int cnt[BSZ];
    __shared__ int cur[BSZ];
    __shared__ int sS[256];
    int b = blockIdx.x, t = threadIdx.x;
    int base = b * CAP;
    int ecnt = cursor[b];
    int nodeBase = b << NBSHIFT;
    cnt[t] = 0;
    __syncthreads();
    for (int j = t; j < ecnt; j += 256)
        atomicAdd(&cnt[pairs[base + j] >> 17], 1);
    __syncthreads();
    int c0 = cnt[t];
    sS[t] = c0; __syncthreads();
    for (int off = 1; off < 256; off <<= 1) {
        int x = (t >= off) ? sS[t - off] : 0;
        __syncthreads();
        sS[t] += x;
        __syncthreads();
    }
    int excl = sS[t] - c0;
    cur[t] = excl;
    int g = nodeBase + t;
    if (g < N) { row_start[g] = base + excl; row_end[g] = base + excl + c0; }
    __syncthreads();
    for (int j = t; j < ecnt; j += 256) {
        unsigned p = pairs[base + j];
        int r = atomicAdd(&cur[p >> 17], 1);
        csr_src[base + r] = (int)(p & 0x1FFFFu);
    }
}

// ---------------- per-dst-node softmax + aggregation: single pass ----------------
// Latency-bound fix: phase 1 loads a chunk of up to 64 edge indices COALESCED
// (lane l <- cs[base+l]), gathers a_s in parallel across all 64 lanes, and
// computes w = exp(leaky(...)) per lane — the serial idx->a_s->exp chain is gone.
// Phase 2 broadcasts (idx, w) from registers via __shfl (no memory dep) and each
// quarter-wave issues 4 independent 16B xs gathers per iteration (16 in flight
// per wave). Chunk is padded to a multiple of 4 with w=0/idx=0 lanes so all
// quads run identical trip counts (no divergence; padded gathers contribute 0).

#define ACC_EDGE(u, wj)  do {                                   \
    const __half2* _h2 = (const __half2*)&(u);                  \
    _Pragma("unroll")                                           \
    for (int _k = 0; _k < 4; _k++) {                            \
        float2 _f = __half22float2(_h2[_k]);                    \
        acc[2 * _k]     += (wj) * _f.x;                         \
        acc[2 * _k + 1] += (wj) * _f.y;                         \
    }                                                           \
} while (0)

template <bool HEAD>
__global__ __launch_bounds__(256) void k_agg(const int* __restrict__ csr_src, const int* __restrict__ row_start,
                                             const int* __restrict__ row_end,
                                             const float* __restrict__ a_s, const float* __restrict__ a_d,
                                             const __half* __restrict__ xs, const float* __restrict__ bias,
                                             const float* __restrict__ Wl, const float* __restrict__ bl,
                                             void* __restrict__ outv, int N) {
    int t = threadIdx.x; int wv = t >> 6, l = t & 63;
    int n = blockIdx.x * 4 + wv;
    if (n >= N) return;   // wave-uniform guard
    int rs = row_start[n], re = row_end[n];
    int deg = re - rs;
    float adn = a_d[n];
    int q = l >> 4;
    int c = (l & 15) * 8;
    const int* cs = csr_src + rs;

    float acc[8];
#pragma unroll
    for (int k = 0; k < 8; k++) acc[k] = 0.f;
    float dnl = 0.f;

    for (int base = 0; base < deg; base += 64) {
        int m = deg - base; if (m > 64) m = 64;
        // phase 1: parallel weight compute (coalesced index load, parallel a_s gather)
        int idx = 0; float w = 0.f;
        if (l < m) {
            idx = cs[base + l];
            float tv = a_s[idx] + adn;
            tv = tv > 0.f ? tv : 0.2f * tv;
            w = __expf(tv);
        }
        dnl += w;
        int mc = (m + 3) & ~3;   // pad: lanes >= m carry w=0, idx=0
        // phase 2: register-broadcast weights, 4 independent gather chains per quad
        int e = q;
        for (; e + 12 < mc; e += 16) {
            int   s0 = __shfl(idx, e);      float w0 = __shfl(w, e);
            int   s1 = __shfl(idx, e + 4);  float w1 = __shfl(w, e + 4);
            int   s2 = __shfl(idx, e + 8);  float w2 = __shfl(w, e + 8);
            int   s3 = __shfl(idx, e + 12); float w3 = __shfl(w, e + 12);
            uint4 u0 = *(const uint4*)&xs[(size_t)s0 * 128 + c];
            uint4 u1 = *(const uint4*)&xs[(size_t)s1 * 128 + c];
            uint4 u2 = *(const uint4*)&xs[(size_t)s2 * 128 + c];
            uint4 u3 = *(const uint4*)&xs[(size_t)s3 * 128 + c];
            ACC_EDGE(u0, w0);
            ACC_EDGE(u1, w1);
            ACC_EDGE(u2, w2);
            ACC_EDGE(u3, w3);
        }
        for (; e + 4 < mc; e += 8) {
            int   s0 = __shfl(idx, e);      float w0 = __shfl(w, e);
            int   s1 = __shfl(idx, e + 4);  float w1 = __shfl(w, e + 4);
            uint4 u0 = *(const uint4*)&xs[(size_t)s0 * 128 + c];
            uint4 u1 = *(const uint4*)&xs[(size_t)s1 * 128 + c];
            ACC_EDGE(u0, w0);
            ACC_EDGE(u1, w1);
        }
        for (; e < mc; e += 4) {
            int   s0 = __shfl(idx, e);      float w0 = __shfl(w, e);
            uint4 u0 = *(const uint4*)&xs[(size_t)s0 * 128 + c];
            ACC_EDGE(u0, w0);
        }
    }

    // full-wave denominator reduce
    dnl += __shfl_xor(dnl, 1);
    dnl += __shfl_xor(dnl, 2);
    dnl += __shfl_xor(dnl, 4);
    dnl += __shfl_xor(dnl, 8);
    dnl += __shfl_xor(dnl, 16);
    dnl += __shfl_xor(dnl, 32);
    float inv = 1.f / (dnl + 1e-16f);

    float hv[8];
    float4 b0 = *(const float4*)&bias[c];
    float4 b1 = *(const float4*)&bias[c + 4];
    float bb[8] = {b0.x, b0.y, b0.z, b0.w, b1.x, b1.y, b1.z, b1.w};
#pragma unroll
    for (int k = 0; k < 8; k++) {
        float v = acc[k];
        v += __shfl_xor(v, 16);
        v += __shfl_xor(v, 32);
        v = v * inv + bb[k];
        hv[k] = v > 0.f ? v : 0.f;
    }

    if (HEAD) {
        float p0 = 0.f, p1 = 0.f;
#pragma unroll
        for (int k = 0; k < 8; k++) {
            p0 += hv[k] * Wl[2 * (c + k)];
            p1 += hv[k] * Wl[2 * (c + k) + 1];
        }
#pragma unroll
        for (int o = 8; o > 0; o >>= 1) { p0 += __shfl_xor(p0, o); p1 += __shfl_xor(p1, o); }
        float* out = (float*)outv;
        if (l == 0) { out[2 * n] = p0 + bl[0]; out[2 * n + 1] = p1 + bl[1]; }
    } else {
        // store hidden state as fp16 (layer-2 GEMM consumes fp16 anyway)
        if (q == 0) {
            __half* hout = (__half*)outv;
            __half hb[8];
#pragma unroll
            for (int k = 0; k < 8; k++) hb[k] = __float2half(hv[k]);
            *(uint4*)&hout[(size_t)n * 128 + c] = *(uint4*)hb;
        }
    }
}

// ---------------- launch ----------------

extern "C" void kernel_launch(void* const* d_in, const int* in_sizes, int n_in,
                              void* d_out, int out_size, void* d_ws, size_t ws_size,
                              hipStream_t stream) {
    const float* x   = (const float*)d_in[0];
    const int*   ei  = (const int*)d_in[1];
    const float* W1s = (const float*)d_in[2];
    const float* W1d = (const float*)d_in[3];
    const float* a1s = (const float*)d_in[4];
    const float* a1d = (const float*)d_in[5];
    const float* b1  = (const float*)d_in[6];
    const float* W2s = (const float*)d_in[7];
    const float* W2d = (const float*)d_in[8];
    const float* a2s = (const float*)d_in[9];
    const float* a2d = (const float*)d_in[10];
    const float* b2  = (const float*)d_in[11];
    const float* Wl  = (const float*)d_in[12];
    const float* bl  = (const float*)d_in[13];
    float* out = (float*)d_out;

    int N = in_sizes[0] / 128;
    int E = in_sizes[1] / 2;
    const int* srcA = ei;
    const int* dstA = ei + E;
    int NB = (N + BSZ - 1) >> NBSHIFT;

    // workspace layout
    __half* xs = (__half*)d_ws;                     // N*128 fp16  (25.6 MB)
    __half* h  = xs + (size_t)N * 128;              // N*128 fp16  (pairs aliases this)
    float* as_ = (float*)(h + (size_t)N * 128);     // N
    float* ad_ = as_ + N;                           // N
    int* row_start = (int*)(ad_ + N);               // N
    int* row_end   = row_start + N;                 // N
    int* csr_src   = row_end + N;                   // NB*CAP (8 MB)
    int* cursor    = csr_src + (size_t)NB * CAP;    // NB (zeroed via memset)
    unsigned* pairs = (unsigned*)h;                 // NB*CAP dwords (8 MB) <= h (25.6 MB);
                                                    // pairs written disp2, read disp3;
                                                    // h first written disp4 — no overlap

    int gb = (N + 63) / 64;
    int EB = (E + 1023) / 1024;
    int ab = (N + 3) / 4;

    // 1) zero bucket cursors (1.5 KB DMA)
    hipMemsetAsync(cursor, 0, (size_t)NB * 4, stream);

    // 2) layer-1 GEMM (self-contained: W-transpose + vd in LDS) fused with kA3
    k_fuse1<<<gb + EB, 256, 0, stream>>>(x, W1s, W1d, a1d, a1s, xs, as_, ad_, N, gb,
                                         srcA, dstA, E, cursor, pairs);

    // 3) per-bucket CSR finalize
    kB_csr<<<NB, 256, 0, stream>>>(pairs, cursor, row_start, row_end, csr_src, N);

    // 4) layer-1 aggregation (writes fp16 h)
    k_agg<false><<<ab, 256, 0, stream>>>(csr_src, row_start, row_end, as_, ad_, xs, b1, nullptr, nullptr, h, N);

    // 5) layer-2 GEMM (self-contained, fp16 input)
    k_gemm2<<<gb, 256, 0, stream>>>(h, W2s, W2d, a2d, a2s, xs, as_, ad_, N);

    // 6) layer-2 aggregation + head
    k_agg<true><<<ab, 256, 0, stream>>>(csr_src, row_start, row_end, as_, ad_, xs, b2, Wl, bl, out, N);
}

// Round 2
// 326.075 us; speedup vs baseline: 1.0331x; 1.0260x over previous
//
#include <hip/hip_runtime.h>
#include <hip/hip_fp16.h>

#define NBSHIFT 8
#define BSZ     256     // nodes per bucket
#define CAP     5120    // fixed bucket capacity (mean 4092, sigma 64 -> +16 sigma)

typedef _Float16 f16x8 __attribute__((ext_vector_type(8)));
typedef float    f32x4 __attribute__((ext_vector_type(4)));

// ---------------- self-contained MFMA GEMM body ----------------
// Per block: (a) vd = W_d @ att_d into LDS (128 threads, L1-resident row dots);
// (b) W_s transposed+cvt to fp16 LDS sWh[n][k] (coalesced loads, 8B LDS stores);
// then Y(fp16)=X@W via mfma_f32_16x16x32_f16, wave owns 16 rows.
// A-frag from X (f32 input for layer 1, fp16 input for layer 2).
// C/D: col=lane&15, row=quad*4+reg.

#define GEMM_LDS_BYTES (128 * 136 * 2 + 512)

template <bool XHALF>
__device__ __forceinline__ void gemm_body(
        const void* __restrict__ Xv, const float* __restrict__ Ws,
        const float* __restrict__ Wd, const float* __restrict__ attd,
        const float* __restrict__ att,
        __half* __restrict__ Y, float* __restrict__ a_s, float* __restrict__ a_d,
        int N, int blk, char* smem) {
    _Float16 (*sWh)[136] = (_Float16(*)[136])smem;
    float* svd = (float*)(smem + 128 * 136 * 2);
    int t = threadIdx.x;

    // vd[k] = dot(Wd row k, attd)   (t < 128; rows L1-cached across the 32 iters)
    if (t < 128) {
        const float4* wr = (const float4*)&Wd[t * 128];
        const float4* ar = (const float4*)attd;
        float s = 0.f;
#pragma unroll 8
        for (int j = 0; j < 32; j++) {
            float4 w = wr[j], a = ar[j];
            s += w.x * a.x + w.y * a.y + w.z * a.z + w.w * a.w;
        }
        svd[t] = s;
    }
    // sWh[n][k] = (fp16) Ws[k*128+n]; per-j loads coalesced (lanes span n)
#pragma unroll
    for (int i = 0; i < 16; i++) {
        int gid = t + i * 256;       // 0..4095
        int n = gid & 127, kq = gid >> 7;
        _Float16 p[4];
        p[0] = (_Float16)Ws[(kq * 4 + 0) * 128 + n];
        p[1] = (_Float16)Ws[(kq * 4 + 1) * 128 + n];
        p[2] = (_Float16)Ws[(kq * 4 + 2) * 128 + n];
        p[3] = (_Float16)Ws[(kq * 4 + 3) * 128 + n];
        *(uint2*)&sWh[n][kq * 4] = *(uint2*)p;
    }
    __syncthreads();

    int l = t & 63, wv = t >> 6;
    int quad = l >> 4, lm = l & 15;
    int rbase = blk * 64 + wv * 16;
    int arow = rbase + lm;
    bool rok = arow < N;

    f32x4 acc[8];
#pragma unroll
    for (int c = 0; c < 8; c++) acc[c] = (f32x4){0.f, 0.f, 0.f, 0.f};
    float adp = 0.f;

#pragma unroll
    for (int kc = 0; kc < 4; kc++) {
        int k0 = kc * 32 + quad * 8;
        float xf[8];
        f16x8 af;
        if constexpr (XHALF) {
            const __half* xrow = (const __half*)Xv + (size_t)arow * 128;
            if (rok) {
                af = *(const f16x8*)&xrow[k0];
            } else {
#pragma unroll
                for (int j = 0; j < 8; j++) af[j] = (_Float16)0.f;
            }
#pragma unroll
            for (int j = 0; j < 8; j++) xf[j] = (float)af[j];
        } else {
            const float* xrow = (const float*)Xv + (size_t)arow * 128;
            if (rok) {
                *(float4*)&xf[0] = *(const float4*)&xrow[k0];
                *(float4*)&xf[4] = *(const float4*)&xrow[k0 + 4];
            } else {
#pragma unroll
                for (int j = 0; j < 8; j++) xf[j] = 0.f;
            }
#pragma unroll
            for (int j = 0; j < 8; j++) af[j] = (_Float16)xf[j];
        }
        float4 v0 = *(const float4*)&svd[k0];       // broadcast within quad
        float4 v1 = *(const float4*)&svd[k0 + 4];
        adp += xf[0] * v0.x + xf[1] * v0.y + xf[2] * v0.z + xf[3] * v0.w
             + xf[4] * v1.x + xf[5] * v1.y + xf[6] * v1.z + xf[7] * v1.w;
#pragma unroll
        for (int c = 0; c < 8; c++) {
            f16x8 bf = *(const f16x8*)&sWh[c * 16 + lm][k0];   // col n = c*16+lm
            acc[c] = __builtin_amdgcn_mfma_f32_16x16x32_f16(af, bf, acc[c], 0, 0, 0);
        }
    }

    adp += __shfl_xor(adp, 16);
    adp += __shfl_xor(adp, 32);
    if (quad == 0 && rok) a_d[arow] = adp;

    float attc[8];
#pragma unroll
    for (int c = 0; c < 8; c++) attc[c] = att[c * 16 + lm];
#pragma unroll
    for (int r = 0; r < 4; r++) {
        int grow = rbase + quad * 4 + r;
        bool gok = grow < N;
        float p = 0.f;
#pragma unroll
        for (int c = 0; c < 8; c++) {
            if (gok) Y[(size_t)grow * 128 + c * 16 + lm] = __float2half(acc[c][r]);
            p += acc[c][r] * attc[c];
        }
        p += __shfl_xor(p, 1); p += __shfl_xor(p, 2); p += __shfl_xor(p, 4); p += __shfl_xor(p, 8);
        if (lm == 0 && gok) a_s[grow] = p;
    }
}

// ---------------- FUSED: layer-1 GEMM (blocks < gb) + kA3 pair placement ----------------
__global__ __launch_bounds__(256, 4) void k_fuse1(
        const float* __restrict__ X, const float* __restrict__ W1s,
        const float* __restrict__ W1d, const float* __restrict__ a1d,
        const float* __restrict__ a1s,
        __half* __restrict__ Y, float* __restrict__ a_s, float* __restrict__ a_d, int N, int gb,
        const int* __restrict__ src, const int* __restrict__ dst, int E,
        int* __restrict__ cursor, unsigned* __restrict__ pairs) {
    __shared__ __align__(16) char smem[GEMM_LDS_BYTES];
    int t = threadIdx.x;

    if ((int)blockIdx.x >= gb) {
        // ---- kA3: bucket pair placement (LDS-aggregated claims) ----
        int* hist  = (int*)smem;          // 512 ints
        int* start = hist + 512;          // 512 ints
        hist[t] = 0; hist[t + 256] = 0;
        __syncthreads();
        int e0 = (blockIdx.x - gb) * 1024 + t * 4;
        int d[4], s[4];
        bool full = (e0 + 3 < E);
        if (full) {
            int4 dv = *(const int4*)&dst[e0];
            int4 sv = *(const int4*)&src[e0];
            d[0] = dv.x; d[1] = dv.y; d[2] = dv.z; d[3] = dv.w;
            s[0] = sv.x; s[1] = sv.y; s[2] = sv.z; s[3] = sv.w;
#pragma unroll
            for (int i = 0; i < 4; i++) atomicAdd(&hist[d[i] >> NBSHIFT], 1);
        } else {
#pragma unroll
            for (int i = 0; i < 4; i++) {
                if (e0 + i < E) { d[i] = dst[e0 + i]; s[i] = src[e0 + i]; atomicAdd(&hist[d[i] >> NBSHIFT], 1); }
                else d[i] = -1;
            }
        }
        __syncthreads();
        if (hist[t] > 0)       start[t]       = atomicAdd(&cursor[t],       hist[t]);
        if (hist[t + 256] > 0) start[t + 256] = atomicAdd(&cursor[t + 256], hist[t + 256]);
        __syncthreads();
        hist[t] = 0; hist[t + 256] = 0;   // reuse as rank counters
        __syncthreads();
#pragma unroll
        for (int i = 0; i < 4; i++) {
            if (full || (e0 + i < E)) {
                int b = d[i] >> NBSHIFT;
                int r = atomicAdd(&hist[b], 1);
                pairs[b * CAP + start[b] + r] = ((unsigned)(d[i] & (BSZ - 1)) << 17) | (unsigned)s[i];
            }
        }
        return;
    }

    gemm_body<false>(X, W1s, W1d, a1d, a1s, Y, a_s, a_d, N, blockIdx.x, smem);
}

// ---------------- standalone layer-2 GEMM (fp16 input h) ----------------
__global__ __launch_bounds__(256, 4) void k_gemm2(
        const __half* __restrict__ X, const float* __restrict__ W2s,
        const float* __restrict__ W2d, const float* __restrict__ a2d,
        const float* __restrict__ a2s,
        __half* __restrict__ Y, float* __restrict__ a_s, float* __restrict__ a_d, int N) {
    __shared__ __align__(16) char smem[GEMM_LDS_BYTES];
    gemm_body<true>(X, W2s, W2d, a2d, a2s, Y, a_s, a_d, N, blockIdx.x, smem);
}

// ---------------- kB: per-bucket CSR finalize (counts/scan/place in LDS) ----------------
__global__ __launch_bounds__(256) void kB_csr(const unsigned* __restrict__ pairs,
                                              const int* __restrict__ cursor,
                                              int* __restrict__ row_start, int* __restrict__ row_end,
                                              int* __restrict__ csr_src, int N) {
    __shared__ int cnt[BSZ];
    __shared__ int cur[BSZ];
    __shared__ int sS[256];
    int b = blockIdx.x, t = threadIdx.x;
    int base = b * CAP;
    int ecnt = cursor[b];
    int nodeBase = b << NBSHIFT;
    cnt[t] = 0;
    __syncthreads();
    for (int j = t; j < ecnt; j += 256)
        atomicAdd(&cnt[pairs[base + j] >> 17], 1);
    __syncthreads();
    int c0 = cnt[t];
    sS[t] = c0; __syncthreads();
    for (int off = 1; off < 256; off <<= 1) {
        int x = (t >= off) ? sS[t - off] : 0;
        __syncthreads();
        sS[t] += x;
        __syncthreads();
    }
    int excl = sS[t] - c0;
    cur[t] = excl;
    int g = nodeBase + t;
    if (g < N) { row_start[g] = base + excl; row_end[g] = base + excl + c0; }
    __syncthreads();
    for (int j = t; j < ecnt; j += 256) {
        unsigned p = pairs[base + j];
        int r = atomicAdd(&cur[p >> 17], 1);
        csr_src[base + r] = (int)(p & 0x1FFFFu);
    }
}

// ---------------- per-dst-node softmax + aggregation: single pass ----------------
// Phase 1: chunk of up to 64 edges, coalesced index load + parallel a_s gather +
// exp across all 64 lanes; (idx, w) written to wave-private LDS (int2).
// Phase 2: per quad, 4 independent gather chains; each edge's (idx,w) comes from
// ONE broadcast ds_read_b64 (16 lanes, same address -> conflict-free broadcast).
// Accumulate with v_fma_mix_f32: acc_f32 += w_f32 * x_f16 in one VALU op
// (exact same rounding as cvt+fma). __launch_bounds__(256,6) caps VGPR at ~84
// so the 4x uint4 payloads actually stay in flight (round-1's VGPR=36 compile
// serialized them).

__device__ __forceinline__ void fma_mix2(float& a0, float& a1, unsigned h2, float w) {
    // a0 += (f32)lo_half(h2) * w ; a1 += (f32)hi_half(h2) * w
    asm("v_fma_mix_f32 %0, %1, %2, %0 op_sel_hi:[1,0,0]" : "+v"(a0) : "v"(h2), "v"(w));
    asm("v_fma_mix_f32 %0, %1, %2, %0 op_sel:[1,0,0] op_sel_hi:[1,0,0]" : "+v"(a1) : "v"(h2), "v"(w));
}

#define ACC_MIX(u, wj)  do {                                    \
    const unsigned* _w32 = (const unsigned*)&(u);               \
    fma_mix2(acc[0], acc[1], _w32[0], (wj));                    \
    fma_mix2(acc[2], acc[3], _w32[1], (wj));                    \
    fma_mix2(acc[4], acc[5], _w32[2], (wj));                    \
    fma_mix2(acc[6], acc[7], _w32[3], (wj));                    \
} while (0)

template <bool HEAD>
__global__ __launch_bounds__(256, 6) void k_agg(const int* __restrict__ csr_src, const int* __restrict__ row_start,
                                                const int* __restrict__ row_end,
                                                const float* __restrict__ a_s, const float* __restrict__ a_d,
                                                const __half* __restrict__ xs, const float* __restrict__ bias,
                                                const float* __restrict__ Wl, const float* __restrict__ bl,
                                                void* __restrict__ outv, int N) {
    __shared__ int2 sP[4][64];
    int t = threadIdx.x; int wv = t >> 6, l = t & 63;
    int n = blockIdx.x * 4 + wv;
    if (n >= N) return;   // wave-uniform guard
    int rs = row_start[n], re = row_end[n];
    int deg = re - rs;
    float adn = a_d[n];
    int q = l >> 4;
    int c = (l & 15) * 8;
    const int* cs = csr_src + rs;
    int2* sp = sP[wv];

    float acc[8];
#pragma unroll
    for (int k = 0; k < 8; k++) acc[k] = 0.f;
    float dnl = 0.f;

    for (int base = 0; base < deg; base += 64) {
        int m = deg - base; if (m > 64) m = 64;
        // phase 1: parallel weight compute (coalesced index load, parallel a_s gather)
        int idx = 0; float w = 0.f;
        if (l < m) {
            idx = cs[base + l];
            float tv = a_s[idx] + adn;
            tv = tv > 0.f ? tv : 0.2f * tv;
            w = __expf(tv);
        }
        dnl += w;
        sp[l] = make_int2(idx, __float_as_int(w));   // wave-private; lanes >= m pad (0, 0)
        int mc = (m + 3) & ~3;
        // phase 2: 4 independent gather chains per quad; (idx,w) via broadcast ds_read
        int e = q;
        for (; e + 12 < mc; e += 16) {
            int2 p0 = sp[e];
            int2 p1 = sp[e + 4];
            int2 p2 = sp[e + 8];
            int2 p3 = sp[e + 12];
            uint4 u0 = *(const uint4*)&xs[(size_t)p0.x * 128 + c];
            uint4 u1 = *(const uint4*)&xs[(size_t)p1.x * 128 + c];
            uint4 u2 = *(const uint4*)&xs[(size_t)p2.x * 128 + c];
            uint4 u3 = *(const uint4*)&xs[(size_t)p3.x * 128 + c];
            ACC_MIX(u0, __int_as_float(p0.y));
            ACC_MIX(u1, __int_as_float(p1.y));
            ACC_MIX(u2, __int_as_float(p2.y));
            ACC_MIX(u3, __int_as_float(p3.y));
        }
        for (; e + 4 < mc; e += 8) {
            int2 p0 = sp[e];
            int2 p1 = sp[e + 4];
            uint4 u0 = *(const uint4*)&xs[(size_t)p0.x * 128 + c];
            uint4 u1 = *(const uint4*)&xs[(size_t)p1.x * 128 + c];
            ACC_MIX(u0, __int_as_float(p0.y));
            ACC_MIX(u1, __int_as_float(p1.y));
        }
        for (; e < mc; e += 4) {
            int2 p0 = sp[e];
            uint4 u0 = *(const uint4*)&xs[(size_t)p0.x * 128 + c];
            ACC_MIX(u0, __int_as_float(p0.y));
        }
    }

    // full-wave denominator reduce
    dnl += __shfl_xor(dnl, 1);
    dnl += __shfl_xor(dnl, 2);
    dnl += __shfl_xor(dnl, 4);
    dnl += __shfl_xor(dnl, 8);
    dnl += __shfl_xor(dnl, 16);
    dnl += __shfl_xor(dnl, 32);
    float inv = 1.f / (dnl + 1e-16f);

    float hv[8];
    float4 b0 = *(const float4*)&bias[c];
    float4 b1 = *(const float4*)&bias[c + 4];
    float bb[8] = {b0.x, b0.y, b0.z, b0.w, b1.x, b1.y, b1.z, b1.w};
#pragma unroll
    for (int k = 0; k < 8; k++) {
        float v = acc[k];
        v += __shfl_xor(v, 16);
        v += __shfl_xor(v, 32);
        v = v * inv + bb[k];
        hv[k] = v > 0.f ? v : 0.f;
    }

    if (HEAD) {
        float p0 = 0.f, p1 = 0.f;
#pragma unroll
        for (int k = 0; k < 8; k++) {
            p0 += hv[k] * Wl[2 * (c + k)];
            p1 += hv[k] * Wl[2 * (c + k) + 1];
        }
#pragma unroll
        for (int o = 8; o > 0; o >>= 1) { p0 += __shfl_xor(p0, o); p1 += __shfl_xor(p1, o); }
        float* out = (float*)outv;
        if (l == 0) { out[2 * n] = p0 + bl[0]; out[2 * n + 1] = p1 + bl[1]; }
    } else {
        // store hidden state as fp16 (layer-2 GEMM consumes fp16 anyway)
        if (q == 0) {
            __half* hout = (__half*)outv;
            __half hb[8];
#pragma unroll
            for (int k = 0; k < 8; k++) hb[k] = __float2half(hv[k]);
            *(uint4*)&hout[(size_t)n * 128 + c] = *(uint4*)hb;
        }
    }
}

// ---------------- launch ----------------

extern "C" void kernel_launch(void* const* d_in, const int* in_sizes, int n_in,
                              void* d_out, int out_size, void* d_ws, size_t ws_size,
                              hipStream_t stream) {
    const float* x   = (const float*)d_in[0];
    const int*   ei  = (const int*)d_in[1];
    const float* W1s = (const float*)d_in[2];
    const float* W1d = (const float*)d_in[3];
    const float* a1s = (const float*)d_in[4];
    const float* a1d = (const float*)d_in[5];
    const float* b1  = (const float*)d_in[6];
    const float* W2s = (const float*)d_in[7];
    const float* W2d = (const float*)d_in[8];
    const float* a2s = (const float*)d_in[9];
    const float* a2d = (const float*)d_in[10];
    const float* b2  = (const float*)d_in[11];
    const float* Wl  = (const float*)d_in[12];
    const float* bl  = (const float*)d_in[13];
    float* out = (float*)d_out;

    int N = in_sizes[0] / 128;
    int E = in_sizes[1] / 2;
    const int* srcA = ei;
    const int* dstA = ei + E;
    int NB = (N + BSZ - 1) >> NBSHIFT;

    // workspace layout
    __half* xs = (__half*)d_ws;                     // N*128 fp16  (25.6 MB)
    __half* h  = xs + (size_t)N * 128;              // N*128 fp16  (pairs aliases this)
    float* as_ = (float*)(h + (size_t)N * 128);     // N
    float* ad_ = as_ + N;                           // N
    int* row_start = (int*)(ad_ + N);               // N
    int* row_end   = row_start + N;                 // N
    int* csr_src   = row_end + N;                   // NB*CAP (8 MB)
    int* cursor    = csr_src + (size_t)NB * CAP;    // NB (zeroed via memset)
    unsigned* pairs = (unsigned*)h;                 // NB*CAP dwords (8 MB) <= h (25.6 MB);
                                                    // pairs written disp2, read disp3;
                                                    // h first written disp4 — no overlap

    int gb = (N + 63) / 64;
    int EB = (E + 1023) / 1024;
    int ab = (N + 3) / 4;

    // 1) zero bucket cursors (1.5 KB DMA)
    hipMemsetAsync(cursor, 0, (size_t)NB * 4, stream);

    // 2) layer-1 GEMM (self-contained: W-transpose + vd in LDS) fused with kA3
    k_fuse1<<<gb + EB, 256, 0, stream>>>(x, W1s, W1d, a1d, a1s, xs, as_, ad_, N, gb,
                                         srcA, dstA, E, cursor, pairs);

    // 3) per-bucket CSR finalize
    kB_csr<<<NB, 256, 0, stream>>>(pairs, cursor, row_start, row_end, csr_src, N);

    // 4) layer-1 aggregation (writes fp16 h)
    k_agg<false><<<ab, 256, 0, stream>>>(csr_src, row_start, row_end, as_, ad_, xs, b1, nullptr, nullptr, h, N);

    // 5) layer-2 GEMM (self-contained, fp16 input)
    k_gemm2<<<gb, 256, 0, stream>>>(h, W2s, W2d, a2d, a2s, xs, as_, ad_, N);

    // 6) layer-2 aggregation + head
    k_agg<true><<<ab, 256, 0, stream>>>(csr_src, row_start, row_end, as_, ad_, xs, b2, Wl, bl, out, N);
}